// Round 3
// baseline (993.607 us; speedup 1.0000x reference)
//
#include <hip/hip_runtime.h>

// Problem constants: B=64, E=1024, M=16, N_STEP=32, G=32000, L=8192
typedef unsigned short u16;
typedef unsigned long long ull;
typedef __attribute__((ext_vector_type(4))) float  float4v;
typedef __attribute__((ext_vector_type(8))) short  short8;   // bf16x8 MFMA frag
typedef __attribute__((ext_vector_type(4))) u16    ushort4v;
typedef __attribute__((ext_vector_type(4))) unsigned int uint4v;

__device__ inline u16 f2bf(float f){
  unsigned u = __builtin_bit_cast(unsigned int, f);
  u += 0x7fffu + ((u >> 16) & 1u);          // RNE
  return (u16)(u >> 16);
}
__device__ inline float bf2f(u16 h){
  unsigned u = ((unsigned)h) << 16;
  return __builtin_bit_cast(float, u);
}
__device__ inline short8 pack8s(float4v a, float4v b, float s){
  short8 r;
  r[0]=(short)f2bf(a[0]*s); r[1]=(short)f2bf(a[1]*s); r[2]=(short)f2bf(a[2]*s); r[3]=(short)f2bf(a[3]*s);
  r[4]=(short)f2bf(b[0]*s); r[5]=(short)f2bf(b[1]*s); r[6]=(short)f2bf(b[2]*s); r[7]=(short)f2bf(b[3]*s);
  return r;
}
__device__ inline void blockReduce2(float& s, float& q, float* sh){
  for (int m=32;m>=1;m>>=1){ s += __shfl_xor(s,m,64); q += __shfl_xor(q,m,64); }
  __syncthreads();
  if ((threadIdx.x&63)==0){ int w=threadIdx.x>>6; sh[w]=s; sh[4+w]=q; }
  __syncthreads();
  s = sh[0]+sh[1]+sh[2]+sh[3];
  q = sh[4]+sh[5]+sh[6]+sh[7];
}
__device__ inline void gll16(const u16* g, u16* l){
  __builtin_amdgcn_global_load_lds(
      (const __attribute__((address_space(1))) unsigned int*)g,
      (__attribute__((address_space(3))) unsigned int*)l, 16, 0, 0);
}

// ---------------- fp32 -> bf16 bulk convert ----------------
__global__ void k_cvt(const float* __restrict__ src, u16* __restrict__ dst, int n4){
  int i = blockIdx.x*256 + threadIdx.x;
  if (i < n4){
    float4v v = ((const float4v*)src)[i];
    ushort4v o;
    o[0]=f2bf(v[0]); o[1]=f2bf(v[1]); o[2]=f2bf(v[2]); o[3]=f2bf(v[3]);
    ((ushort4v*)dst)[i] = o;
  }
}

// ---------------- fp32 -> split bf16 (hi + lo residual); also init atomics ----
__global__ void k_cvt2(const float* __restrict__ src, u16* __restrict__ hi,
                       u16* __restrict__ lo, int n4,
                       float* __restrict__ rowsum, float* __restrict__ picked){
  int i = blockIdx.x*256 + threadIdx.x;
  if (i < 2048){ rowsum[i] = 0.f; picked[i] = 0.f; }
  if (i < n4){
    float4v v = ((const float4v*)src)[i];
    ushort4v h, l;
    #pragma unroll
    for (int j=0;j<4;j++){ h[j]=f2bf(v[j]); l[j]=f2bf(v[j]-bf2f((u16)h[j])); }
    ((ushort4v*)hi)[i] = h;
    ((ushort4v*)lo)[i] = l;
  }
}

// ---------------- gather + stdnorm + noise; seeds Krylov k=0 block ----------
// V layout: row = k*128 + s, s=0..63 batch seeds, s=64 bias, s=65..127 zero pad.
__global__ void k_prep(const int* __restrict__ zi, const float* __restrict__ latent,
                       const float* __restrict__ noise, const float* __restrict__ tb,
                       float* __restrict__ z0, u16* __restrict__ V){
  __shared__ float sh[8];
  int b = blockIdx.x;
  if (b == 64){
    for (int e=threadIdx.x;e<1024;e+=256) V[(size_t)64*1024+e] = f2bf(tb[e]);
    for (int r=65;r<128;r++)
      for (int e=threadIdx.x;e<1024;e+=256) V[(size_t)r*1024+e] = 0;
    return;
  }
  const float* lat = latent + (size_t)zi[b]*2048;
  for (int j=0;j<2;j++){
    float s=0.f,q=0.f;
    for (int e=threadIdx.x;e<1024;e+=256){ float v=lat[j*1024+e]; s+=v; q+=v*v; }
    blockReduce2(s,q,sh);
    float sd = sqrtf(fmaxf(0.f,(q - s*s*(1.f/1024.f))*(1.f/1023.f)));
    float fac = 0.113f/(1e-5f+sd);
    for (int e=threadIdx.x;e<1024;e+=256){
      float v = lat[j*1024+e]*fac + (noise[((size_t)b*2+j)*1024+e]-0.5f)*0.05f;
      if (j==0) z0[b*1024+e]=v;
      else      V[(size_t)b*1024+e]=f2bf(v);
    }
  }
}

// ---------------- ek/ev projection: (64 x 16384) = z0 @ Wt, MFMA ----------------
__global__ __launch_bounds__(256) void k_ekev(const float* __restrict__ z0,
    const float* __restrict__ ekw, const float* __restrict__ ekb,
    const float* __restrict__ evw, const float* __restrict__ evb,
    float* __restrict__ ek_raw, float* __restrict__ ev_raw){
  int nb = blockIdx.x;
  const float* wsrc; const float* bsrc; float* dst;
  if (nb < 1024){ wsrc=ekw; bsrc=ekb; dst=ek_raw; }
  else          { wsrc=evw; bsrc=evb; dst=ev_raw; nb -= 1024; }
  int colbase = nb*16;
  int w = threadIdx.x>>6, lane = threadIdx.x&63;
  int m16 = lane&15, q = lane>>4;
  const float* za = z0 + (w*16+m16)*1024 + q*8;
  const float* wb = wsrc + ((size_t)(colbase+m16))*1024 + q*8;
  float4v acc = {0.f,0.f,0.f,0.f};
  for (int kk=0;kk<32;kk++){
    float4v a0 = *(const float4v*)(za + kk*32);
    float4v a1 = *(const float4v*)(za + kk*32 + 4);
    float4v b0 = *(const float4v*)(wb + kk*32);
    float4v b1 = *(const float4v*)(wb + kk*32 + 4);
    short8 af = pack8s(a0,a1,1.f);
    short8 bf = pack8s(b0,b1,1.f);
    acc = __builtin_amdgcn_mfma_f32_16x16x32_bf16(af,bf,acc,0,0,0);
  }
  float bias = bsrc[colbase+m16];
  for (int reg=0;reg<4;reg++){
    int r = w*16 + q*4 + reg;
    dst[(size_t)r*16384 + colbase + m16] = acc[reg] + bias;
  }
}

// ---------------- per-(b,m) stdnorm -> bf16 ----------------
__global__ void k_norm(const float* __restrict__ ek_raw, const float* __restrict__ ev_raw,
                       u16* __restrict__ ek16, u16* __restrict__ ev16){
  __shared__ float sh[8];
  int rr = blockIdx.x;
  const float* src = (rr<1024)? ek_raw : ev_raw;
  u16* dst = (rr<1024)? ek16 : ev16;
  int r = rr & 1023;
  const float* x = src + (size_t)r*1024;
  float s=0.f,q=0.f;
  for (int e=threadIdx.x;e<1024;e+=256){ float v=x[e]; s+=v; q+=v*v; }
  blockReduce2(s,q,sh);
  float fac = 0.113f/(1e-5f+sqrtf(fmaxf(0.f,(q-s*s*(1.f/1024.f))*(1.f/1023.f))));
  u16* o = dst + (size_t)r*1024;
  for (int e=threadIdx.x;e<1024;e+=256) o[e] = f2bf(x[e]*fac);
}

// ---------------- bf16 transpose, 2 planes (1024x1024) ----------------
__global__ __launch_bounds__(256) void k_tr(const u16* __restrict__ S1, u16* __restrict__ D1,
                                            const u16* __restrict__ S2, u16* __restrict__ D2){
  __shared__ u16 t[64*65];
  const u16* src = blockIdx.z ? S2 : S1;
  u16* dst = blockIdx.z ? D2 : D1;
  int bx = blockIdx.x, by = blockIdx.y, tid = threadIdx.x;
  #pragma unroll
  for (int i=0;i<4;i++){
    int r = i*16 + (tid>>4), c0 = (tid&15)*4;
    ushort4v v = *(const ushort4v*)(src + (size_t)(by*64+r)*1024 + bx*64 + c0);
    #pragma unroll
    for (int j=0;j<4;j++) t[(c0+j)*65 + r] = v[j];
  }
  __syncthreads();
  #pragma unroll
  for (int i=0;i<4;i++){
    int r2 = i*16 + (tid>>4), c0 = (tid&15)*4;
    ushort4v o;
    #pragma unroll
    for (int j=0;j<4;j++) o[j] = t[r2*65 + c0 + j];
    *(ushort4v*)(dst + (size_t)(bx*64+r2)*1024 + by*64 + c0) = o;
  }
}

// ---------------- split-bf16 matrix square: C = (Ah+Al)(Bh+Bl)^T, 3-term -------
// 128x128 tile, swizzled LDS staging. Output split hi/lo (lo optional).
__global__ __launch_bounds__(256) void k_sq(const u16* __restrict__ Ah, const u16* __restrict__ Al,
    const u16* __restrict__ Bh, const u16* __restrict__ Bl,
    u16* __restrict__ Ch, u16* __restrict__ Cl){
  __shared__ u16 sAh[128*64], sAl[128*64], sBh[128*64], sBl[128*64];
  int bm = blockIdx.x, bn = blockIdx.y, tid = threadIdx.x;
  int w = tid>>6, lane = tid&63;
  int wm = w>>1, wn = w&1, m16 = lane&15, q = lane>>4;
  const u16* Abh = Ah + (size_t)bm*128*1024;
  const u16* Abl = Al + (size_t)bm*128*1024;
  const u16* Bbh = Bh + (size_t)bn*128*1024;
  const u16* Bbl = Bl + (size_t)bn*128*1024;
  float4v acc[4][4];
  for (int i=0;i<4;i++) for (int j=0;j<4;j++) acc[i][j] = (float4v){0.f,0.f,0.f,0.f};
  for (int kt=0;kt<16;kt++){
    int kb = kt*64;
    for (int rd=0; rd<4; rd++){
      int c = rd*256 + tid;
      int row = c>>3;
      int kq = (c&7) ^ (row&7);
      size_t go = (size_t)row*1024 + kb + kq*8;
      gll16(Abh+go, &sAh[c*8]); gll16(Abl+go, &sAl[c*8]);
      gll16(Bbh+go, &sBh[c*8]); gll16(Bbl+go, &sBl[c*8]);
    }
    __syncthreads();
    for (int s=0;s<2;s++){
      int kq = s*4 + q;
      short8 ah[4], al[4], bh[4], bl[4];
      for (int i=0;i<4;i++){
        int row = wm*64 + i*16 + m16;
        int offA = (row*8 + (kq ^ (row&7)))*8;
        ah[i] = *(const short8*)&sAh[offA];
        al[i] = *(const short8*)&sAl[offA];
        int col = wn*64 + i*16 + m16;
        int offB = (col*8 + (kq ^ (col&7)))*8;
        bh[i] = *(const short8*)&sBh[offB];
        bl[i] = *(const short8*)&sBl[offB];
      }
      for (int i=0;i<4;i++)
        for (int j=0;j<4;j++){
          acc[i][j] = __builtin_amdgcn_mfma_f32_16x16x32_bf16(al[i],bh[j],acc[i][j],0,0,0);
          acc[i][j] = __builtin_amdgcn_mfma_f32_16x16x32_bf16(ah[i],bl[j],acc[i][j],0,0,0);
          acc[i][j] = __builtin_amdgcn_mfma_f32_16x16x32_bf16(ah[i],bh[j],acc[i][j],0,0,0);
        }
    }
    __syncthreads();
  }
  for (int i=0;i<4;i++)
    for (int reg=0;reg<4;reg++){
      int r = bm*128 + wm*64 + i*16 + q*4 + reg;
      for (int j=0;j<4;j++){
        int c = bn*128 + wn*64 + j*16 + m16;
        float v = acc[i][j][reg];
        u16 h = f2bf(v);
        Ch[(size_t)r*1024+c] = h;
        if (Cl) Cl[(size_t)r*1024+c] = f2bf(v - bf2f(h));
      }
    }
}

// ---------------- Krylov stage GEMM: C[M x 1024] = A[M x 1024] @ Bh^T ---------
__global__ __launch_bounds__(256) void k_stage(const u16* __restrict__ A,
    const u16* __restrict__ Bh, u16* __restrict__ C){
  __shared__ u16 sA[128*64], sB[128*64];
  int bm = blockIdx.x, bn = blockIdx.y, tid = threadIdx.x;
  int w = tid>>6, lane = tid&63;
  int wm = w>>1, wn = w&1, m16 = lane&15, q = lane>>4;
  const u16* Ab = A + (size_t)bm*128*1024;
  const u16* Bb = Bh + (size_t)bn*128*1024;
  float4v acc[4][4];
  for (int i=0;i<4;i++) for (int j=0;j<4;j++) acc[i][j] = (float4v){0.f,0.f,0.f,0.f};
  for (int kt=0;kt<16;kt++){
    int kb = kt*64;
    for (int rd=0; rd<4; rd++){
      int c = rd*256 + tid;
      int row = c>>3;
      int kq = (c&7) ^ (row&7);
      size_t go = (size_t)row*1024 + kb + kq*8;
      gll16(Ab+go, &sA[c*8]);
      gll16(Bb+go, &sB[c*8]);
    }
    __syncthreads();
    for (int s=0;s<2;s++){
      int kq = s*4 + q;
      short8 af[4], bf[4];
      for (int i=0;i<4;i++){
        int row = wm*64 + i*16 + m16;
        af[i] = *(const short8*)&sA[(row*8 + (kq ^ (row&7)))*8];
        int col = wn*64 + i*16 + m16;
        bf[i] = *(const short8*)&sB[(col*8 + (kq ^ (col&7)))*8];
      }
      for (int i=0;i<4;i++)
        for (int j=0;j<4;j++)
          acc[i][j] = __builtin_amdgcn_mfma_f32_16x16x32_bf16(af[i],bf[j],acc[i][j],0,0,0);
    }
    __syncthreads();
  }
  for (int i=0;i<4;i++)
    for (int reg=0;reg<4;reg++){
      int r = bm*128 + wm*64 + i*16 + q*4 + reg;
      for (int j=0;j<4;j++){
        int c = bn*128 + wn*64 + j*16 + m16;
        C[(size_t)r*1024+c] = f2bf(acc[i][j][reg]);
      }
    }
}

// ---------------- per-batch Gram G[64x64], proj P[64x16], sums S[64] ----------
// basis kappa<32: row kappa*128+b (z-part); kappa>=32: row (kappa-32)*128+64 (bias).
__global__ __launch_bounds__(256) void k_gram(const u16* __restrict__ V,
    const u16* __restrict__ ek16, float* __restrict__ G, float* __restrict__ S,
    float* __restrict__ P){
  int b = blockIdx.x, tid = threadIdx.x;
  int w = tid>>6, lane = tid&63, m16 = lane&15, q = lane>>4;
  int kap = w*16 + m16;
  size_t arow = (kap<32) ? ((size_t)kap*128 + b) : ((size_t)(kap-32)*128 + 64);
  const u16* ap = V + arow*1024 + q*8;
  const u16* bp[5];
  #pragma unroll
  for (int j=0;j<4;j++){
    int y = j*16 + m16;
    size_t br = (y<32) ? ((size_t)y*128 + b) : ((size_t)(y-32)*128 + 64);
    bp[j] = V + br*1024 + q*8;
  }
  bp[4] = ek16 + ((size_t)(b*16 + m16))*1024 + q*8;
  float4v acc[5];
  #pragma unroll
  for (int j=0;j<5;j++) acc[j] = (float4v){0.f,0.f,0.f,0.f};
  for (int kk=0;kk<32;kk++){
    short8 a8 = *(const short8*)(ap + kk*32);
    #pragma unroll
    for (int j=0;j<5;j++){
      short8 b8 = *(const short8*)(bp[j] + kk*32);
      acc[j] = __builtin_amdgcn_mfma_f32_16x16x32_bf16(a8,b8,acc[j],0,0,0);
    }
  }
  int kbase = w*16 + q*4;
  for (int j=0;j<5;j++)
    for (int reg=0;reg<4;reg++){
      int y = j*16 + m16;
      float v = acc[j][reg];
      if (j<4) G[((size_t)b*64 + kbase+reg)*64 + y] = v;
      else     P[((size_t)b*64 + kbase+reg)*16 + (y-64)] = v;
    }
  // element sums S[kappa]
  __shared__ float red[256];
  int kap2 = tid>>2, seg = tid&3;
  size_t row2 = (kap2<32) ? ((size_t)kap2*128 + b) : ((size_t)(kap2-32)*128 + 64);
  const u16* vp = V + row2*1024 + seg*256;
  float sum = 0.f;
  for (int i=0;i<32;i++){
    short8 v8 = *(const short8*)(vp + i*8);
    #pragma unroll
    for (int e=0;e<8;e++) sum += bf2f((u16)v8[e]);
  }
  red[tid] = sum;
  __syncthreads();
  if (tid<64) S[b*64+tid] = red[tid*4]+red[tid*4+1]+red[tid*4+2]+red[tid*4+3];
}

// ---------------- scalar Krylov scan: 32 sequential steps, intra-block only ----
// gamma recurrence: gamma' = (f/2) shift(gamma) + (1/2) e_{kappa=32}
__global__ __launch_bounds__(64) void k_attscan(const float* __restrict__ G,
    const float* __restrict__ S, const float* __restrict__ P, float* __restrict__ att){
  __shared__ __align__(16) float gam[64];
  __shared__ float pl[1024];
  int b = blockIdx.x, lane = threadIdx.x;
  float gr[64];
  {
    const float4v* gp = (const float4v*)(G + ((size_t)b*64 + lane)*64);
    #pragma unroll
    for (int i=0;i<16;i++){
      float4v v = gp[i];
      gr[i*4+0]=v[0]; gr[i*4+1]=v[1]; gr[i*4+2]=v[2]; gr[i*4+3]=v[3];
    }
  }
  float s_own = S[b*64 + lane];
  for (int i=lane;i<1024;i+=64) pl[i] = P[(size_t)b*1024 + i];
  float g_own = (lane==0) ? 1.f : 0.f;
  gam[lane] = g_own;
  __syncthreads();
  for (int t=0;t<32;t++){
    float r = 0.f;
    #pragma unroll
    for (int i=0;i<16;i++){
      float4v gv = *(const float4v*)&gam[i*4];
      r += gr[i*4+0]*gv[0] + gr[i*4+1]*gv[1] + gr[i*4+2]*gv[2] + gr[i*4+3]*gv[3];
    }
    float qq = g_own*r, sm = g_own*s_own;
    for (int m=32;m>=1;m>>=1){ qq += __shfl_xor(qq,m,64); sm += __shfl_xor(sm,m,64); }
    float var = (qq - sm*sm*(1.f/1024.f))*(1.f/1023.f);
    float f = 0.113f/(1e-5f + sqrtf(fmaxf(0.f,var)));
    float sc = 0.f;
    if (lane < 16){
      #pragma unroll
      for (int k2=0;k2<64;k2++) sc += gam[k2]*pl[k2*16+lane];
      sc *= f;
    }
    float mx = sc;
    for (int m=8;m>=1;m>>=1) mx = fmaxf(mx, __shfl_xor(mx,m,64));
    float ex = __expf(sc - mx), ss = ex;
    for (int m=8;m>=1;m>>=1) ss += __shfl_xor(ss,m,64);
    if (lane<16) att[((size_t)b*32+t)*16 + lane] = ex/ss;
    float prev = (lane==0 || lane==32) ? 0.f : gam[lane-1];
    __syncthreads();
    g_own = (lane==32) ? 0.5f : 0.5f*f*prev;
    gam[lane] = g_own;
    __syncthreads();
  }
}

// ---------------- emit: zs[b,t] = sum_m att[b,t,m] * ev[b,m,:] ----------------
__global__ __launch_bounds__(256) void k_emit(const float* __restrict__ att,
    const u16* __restrict__ ev16, u16* __restrict__ zs16){
  __shared__ float a_s[16];
  int bid = blockIdx.x, tid = threadIdx.x;
  int b = bid>>5, t = bid&31;
  if (tid<16) a_s[tid] = att[((size_t)b*32+t)*16 + tid];
  __syncthreads();
  float o0=0,o1=0,o2=0,o3=0;
  #pragma unroll
  for (int m=0;m<16;m++){
    float a = a_s[m];
    ushort4v v = *(const ushort4v*)(ev16 + ((size_t)(b*16+m))*1024 + tid*4);
    o0 += a*bf2f(v[0]); o1 += a*bf2f(v[1]); o2 += a*bf2f(v[2]); o3 += a*bf2f(v[3]);
  }
  u16* dst = zs16 + (size_t)bid*1024 + tid*4;
  dst[0]=f2bf(o0); dst[1]=f2bf(o1); dst[2]=f2bf(o2); dst[3]=f2bf(o3);
}

// ---------------- logits GEMM 2048x32000x1024 bf16, 256^2 tile ---------------
// 8-phase schedule w/ counted vmcnt (T3+T4) + setprio (T5).
// LDS: 8 staging units of 16KB: [dbuf][mat(A/B)][ks] each [g:4][row:256] x 16B
// granules. Reads are 16-lane-contiguous 256B windows -> conflict-free.
// Per K-tile (BK=64): 4 phases (ks x col-half); A-frags read at ch0, reused ch1.
// Stage schedule during tile t: ph0: A_{t+1}.ks1, ph1: B_{t+1}.ks1,
//   ph2: A_{t+2}.ks0, ph3: B_{t+2}.ks0  (targets proven retired a phase earlier).
// vmcnt(4) once per tile at end of ph3 (before final barrier); vmcnt(0) at t=14.
__global__ __launch_bounds__(512,2) void k_logits(const u16* __restrict__ A,
    const u16* __restrict__ Bt, const float* __restrict__ vb,
    const int* __restrict__ y, float* __restrict__ rowsum, float* __restrict__ picked){
  __shared__ __align__(16) u16 sU[65536];   // 128 KB
  int lin = blockIdx.y*8 + blockIdx.x;
  int newlin = (lin&7)*125 + (lin>>3);      // XCD-chunked bijective swizzle
  int bm = newlin&7, bn = newlin>>3;
  int tid = threadIdx.x;
  int w = tid>>6, lane = tid&63;
  int wm = w>>2, wn = w&3, m16 = lane&15, q = lane>>4;
  const u16* Ab = A  + (size_t)bm*256*1024;
  const u16* Bb = Bt + (size_t)bn*256*1024;
  float4v acc[8][4];
  #pragma unroll
  for (int i=0;i<8;i++)
    #pragma unroll
    for (int j=0;j<4;j++) acc[i][j] = (float4v){0.f,0.f,0.f,0.f};

  // stage unit (16KB): dbuf d, mat (0=A,1=B), k-slice ks, of K-tile tt.
  // LDS granule = unit*1024 + g*256 + row ; global src = M[row][tt*64+ks*32+g*8]
  #define SUNIT(d_, mat_, ks_, tt_) do {                                   \
    const u16* src_ = (mat_) ? Bb : Ab;                                    \
    int baseg_ = (((d_)*2 + (mat_))*2 + (ks_))*1024;                       \
    _Pragma("unroll")                                                      \
    for (int l_=0;l_<2;l_++){                                              \
      int s_ = l_*512 + tid;                                               \
      gll16(src_ + (size_t)(s_&255)*1024 + (tt_)*64 + (ks_)*32 + (s_>>8)*8,\
            &sU[(baseg_ + s_)*8]);                                         \
    }                                                                      \
  } while(0)

  // prologue: tile0 (4 units) + tile1 ks0 units; wait first 4 units.
  SUNIT(0,0,0,0); SUNIT(0,1,0,0); SUNIT(0,0,1,0); SUNIT(0,1,1,0);
  SUNIT(1,0,0,1); SUNIT(1,1,0,1);
  asm volatile("s_waitcnt vmcnt(4)" ::: "memory");
  __builtin_amdgcn_s_barrier();
  asm volatile("" ::: "memory");

  short8 af[8], bf[2];
  for (int t=0; t<16; t++){
    int cur = t&1;
    #pragma unroll
    for (int ph=0; ph<4; ph++){
      int ks = ph>>1, ch = ph&1;
      if (ch==0){
        int agbase = ((cur*4 + ks)*4 + q)*256;          // A unit: mat=0
        #pragma unroll
        for (int i=0;i<8;i++)
          af[i] = *(const short8*)&sU[(agbase + wm*128 + i*16 + m16)*8];
      }
      int bgbase = (((cur*2+1)*2 + ks)*4 + q)*256;      // B unit: mat=1
      #pragma unroll
      for (int j=0;j<2;j++)
        bf[j] = *(const short8*)&sU[(bgbase + wn*64 + (ch*2+j)*16 + m16)*8];
      // stage one unit per phase (skip past the last tiles)
      if      (ph==0){ if (t+1<16) SUNIT((t+1)&1, 0, 1, t+1); }
      else if (ph==1){ if (t+1<16) SUNIT((t+1)&1, 1, 1, t+1); }
      else if (ph==2){ if (t+2<16) SUNIT(cur,     0, 0, t+2); }
      else           { if (t+2<16) SUNIT(cur,     1, 0, t+2); }
      __builtin_amdgcn_s_barrier();
      asm volatile("" ::: "memory");
      __builtin_amdgcn_s_setprio(1);
      #pragma unroll
      for (int i=0;i<8;i++){
        acc[i][ch*2+0] = __builtin_amdgcn_mfma_f32_16x16x32_bf16(af[i],bf[0],acc[i][ch*2+0],0,0,0);
        acc[i][ch*2+1] = __builtin_amdgcn_mfma_f32_16x16x32_bf16(af[i],bf[1],acc[i][ch*2+1],0,0,0);
      }
      __builtin_amdgcn_s_setprio(0);
      if (ph==3){
        if (t==14)     asm volatile("s_waitcnt vmcnt(0)" ::: "memory");
        else if (t<14) asm volatile("s_waitcnt vmcnt(4)" ::: "memory");
      }
      __builtin_amdgcn_s_barrier();
      asm volatile("" ::: "memory");
    }
  }
  #undef SUNIT

  // fused logsumexp epilogue (unchanged)
  #pragma unroll
  for (int i=0;i<8;i++){
    #pragma unroll
    for (int reg=0;reg<4;reg++){
      int r = bm*256 + wm*128 + i*16 + q*4 + reg;
      int yt = y[r];
      float rs = 0.f;
      #pragma unroll
      for (int j=0;j<4;j++){
        int gcol = bn*256 + wn*64 + j*16 + m16;
        float val = acc[i][j][reg] + vb[gcol];
        rs += __expf(val);
        if (gcol == yt) picked[r] = val;
      }
      for (int mm=1;mm<16;mm<<=1) rs += __shfl_xor(rs,mm,16);
      if (m16==0) atomicAdd(&rowsum[r], rs);
    }
  }
}

__global__ void k_final(const float* __restrict__ picked, const float* __restrict__ rowsum,
                        float* __restrict__ out){
  int r = blockIdx.x*256 + threadIdx.x;
  if (r < 2048) out[r] = picked[r] - logf(rowsum[r]);
}

extern "C" void kernel_launch(void* const* d_in, const int* in_sizes, int n_in,
                              void* d_out, int out_size, void* d_ws, size_t ws_size,
                              hipStream_t stream){
  (void)in_sizes; (void)n_in; (void)out_size; (void)ws_size;
  const int*   zi     = (const int*)d_in[0];
  const int*   y      = (const int*)d_in[1];
  const float* noise  = (const float*)d_in[2];
  const float* latent = (const float*)d_in[3];
  const float* transw = (const float*)d_in[4];
  const float* transb = (const float*)d_in[5];
  const float* ekw    = (const float*)d_in[6];
  const float* ekb    = (const float*)d_in[7];
  const float* evw    = (const float*)d_in[8];
  const float* evb    = (const float*)d_in[9];
  const float* vw     = (const float*)d_in[10];
  const float* vbias  = (const float*)d_in[11];
  float* out = (float*)d_out;

  const size_t MPLANE = (size_t)1024*1024;   // one 1024x1024 bf16 plane (elems)
  char* p = (char*)d_ws;
  u16* vocab16 = (u16*)p;  p += (size_t)32000*1024*2;
  u16* Whi  = (u16*)p;  p += MPLANE*2;
  u16* Wlo  = (u16*)p;  p += MPLANE*2;
  u16* P1h  = (u16*)p;  p += MPLANE*2;
  u16* P1l  = (u16*)p;  p += MPLANE*2;
  u16* T2h  = (u16*)p;  p += MPLANE*2;
  u16* T2l  = (u16*)p;  p += MPLANE*2;
  u16* P2h  = (u16*)p;  p += MPLANE*2;
  u16* P2l  = (u16*)p;  p += MPLANE*2;
  u16* T4h  = (u16*)p;  p += MPLANE*2;
  u16* T4l  = (u16*)p;  p += MPLANE*2;
  u16* P4h  = (u16*)p;  p += MPLANE*2;
  u16* P4l  = (u16*)p;  p += MPLANE*2;
  u16* T8h  = (u16*)p;  p += MPLANE*2;
  u16* T8l  = (u16*)p;  p += MPLANE*2;
  u16* P8h  = (u16*)p;  p += MPLANE*2;
  u16* P8l  = (u16*)p;  p += MPLANE*2;
  u16* T16h = (u16*)p;  p += MPLANE*2;
  u16* V    = (u16*)p;  p += (size_t)4096*1024*2;   // 32 k-blocks x 128 rows
  u16* zs16 = (u16*)p;  p += (size_t)2048*1024*2;
  u16* ek16 = (u16*)p;  p += (size_t)64*16*1024*2;
  u16* ev16 = (u16*)p;  p += (size_t)64*16*1024*2;
  float* ekraw = (float*)p; p += (size_t)64*16384*4;
  float* evraw = (float*)p; p += (size_t)64*16384*4;
  float* z0    = (float*)p; p += (size_t)64*1024*4;
  float* G     = (float*)p; p += (size_t)64*64*64*4;
  float* S     = (float*)p; p += (size_t)64*64*4;
  float* Pk    = (float*)p; p += (size_t)64*64*16*4;
  float* att   = (float*)p; p += (size_t)64*32*16*4;
  float* rowsum= (float*)p; p += (size_t)2048*4;
  float* picked= (float*)p; p += (size_t)2048*4;

  hipLaunchKernelGGL(k_cvt2, dim3(1024),  dim3(256), 0, stream, transw, Whi, Wlo, 1024*1024/4, rowsum, picked);
  hipLaunchKernelGGL(k_cvt,  dim3(32000), dim3(256), 0, stream, vw, vocab16, 32000*1024/4);
  hipLaunchKernelGGL(k_prep, dim3(65),    dim3(256), 0, stream, zi, latent, noise, transb, z0, V);
  hipLaunchKernelGGL(k_ekev, dim3(2048),  dim3(256), 0, stream, z0, ekw, ekb, evw, evb, ekraw, evraw);
  hipLaunchKernelGGL(k_norm, dim3(2048),  dim3(256), 0, stream, ekraw, evraw, ek16, ev16);

  // power chain: W^2, W^4, W^8, W^16 in split bf16 (hi+lo; W^16 hi only)
  hipLaunchKernelGGL(k_tr, dim3(16,16,2), dim3(256), 0, stream, Whi, P1h, Wlo, P1l);
  hipLaunchKernelGGL(k_sq, dim3(8,8),     dim3(256), 0, stream, Whi, Wlo, P1h, P1l, T2h, T2l);
  hipLaunchKernelGGL(k_tr, dim3(16,16,2), dim3(256), 0, stream, T2h, P2h, T2l, P2l);
  hipLaunchKernelGGL(k_sq, dim3(8,8),     dim3(256), 0, stream, T2h, T2l, P2h, P2l, T4h, T4l);
  hipLaunchKernelGGL(k_tr, dim3(16,16,2), dim3(256), 0, stream, T4h, P4h, T4l, P4l);
  hipLaunchKernelGGL(k_sq, dim3(8,8),     dim3(256), 0, stream, T4h, T4l, P4h, P4l, T8h, T8l);
  hipLaunchKernelGGL(k_tr, dim3(16,16,2), dim3(256), 0, stream, T8h, P8h, T8l, P8l);
  hipLaunchKernelGGL(k_sq, dim3(8,8),     dim3(256), 0, stream, T8h, T8l, P8h, P8l, T16h, (u16*)nullptr);

  // Krylov stages: V[k+2^j .. ] = V[k ..] @ (W^{2^j})^T
  hipLaunchKernelGGL(k_stage, dim3(1,8),  dim3(256), 0, stream, V, Whi,  V + (size_t)1*128*1024);
  hipLaunchKernelGGL(k_stage, dim3(2,8),  dim3(256), 0, stream, V, T2h,  V + (size_t)2*128*1024);
  hipLaunchKernelGGL(k_stage, dim3(4,8),  dim3(256), 0, stream, V, T4h,  V + (size_t)4*128*1024);
  hipLaunchKernelGGL(k_stage, dim3(8,8),  dim3(256), 0, stream, V, T8h,  V + (size_t)8*128*1024);
  hipLaunchKernelGGL(k_stage, dim3(16,8), dim3(256), 0, stream, V, T16h, V + (size_t)16*128*1024);

  hipLaunchKernelGGL(k_gram,    dim3(64),   dim3(256), 0, stream, V, ek16, G, S, Pk);
  hipLaunchKernelGGL(k_attscan, dim3(64),   dim3(64),  0, stream, G, S, Pk, att);
  hipLaunchKernelGGL(k_emit,    dim3(2048), dim3(256), 0, stream, att, ev16, zs16);
  hipLaunchKernelGGL(k_logits,  dim3(8,125), dim3(512), 0, stream, zs16, vocab16, vbias, y, rowsum, picked);
  hipLaunchKernelGGL(k_final,   dim3(8),    dim3(256), 0, stream, picked, rowsum, out);
}

// Round 4
// 912.397 us; speedup vs baseline: 1.0890x; 1.0890x over previous
//
#include <hip/hip_runtime.h>

// Problem constants: B=64, E=1024, M=16, N_STEP=32, G=32000, L=8192
typedef unsigned short u16;
typedef unsigned long long ull;
typedef __attribute__((ext_vector_type(4))) float  float4v;
typedef __attribute__((ext_vector_type(8))) short  short8;   // bf16x8 MFMA frag
typedef __attribute__((ext_vector_type(4))) u16    ushort4v;
typedef __attribute__((ext_vector_type(4))) unsigned int uint4v;

__device__ inline u16 f2bf(float f){
  unsigned u = __builtin_bit_cast(unsigned int, f);
  u += 0x7fffu + ((u >> 16) & 1u);          // RNE
  return (u16)(u >> 16);
}
__device__ inline float bf2f(u16 h){
  unsigned u = ((unsigned)h) << 16;
  return __builtin_bit_cast(float, u);
}
__device__ inline short8 pack8s(float4v a, float4v b, float s){
  short8 r;
  r[0]=(short)f2bf(a[0]*s); r[1]=(short)f2bf(a[1]*s); r[2]=(short)f2bf(a[2]*s); r[3]=(short)f2bf(a[3]*s);
  r[4]=(short)f2bf(b[0]*s); r[5]=(short)f2bf(b[1]*s); r[6]=(short)f2bf(b[2]*s); r[7]=(short)f2bf(b[3]*s);
  return r;
}
__device__ inline void blockReduce2(float& s, float& q, float* sh){
  for (int m=32;m>=1;m>>=1){ s += __shfl_xor(s,m,64); q += __shfl_xor(q,m,64); }
  __syncthreads();
  if ((threadIdx.x&63)==0){ int w=threadIdx.x>>6; sh[w]=s; sh[4+w]=q; }
  __syncthreads();
  s = sh[0]+sh[1]+sh[2]+sh[3];
  q = sh[4]+sh[5]+sh[6]+sh[7];
}
__device__ inline void gll16(const u16* g, u16* l){
  __builtin_amdgcn_global_load_lds(
      (const __attribute__((address_space(1))) unsigned int*)g,
      (__attribute__((address_space(3))) unsigned int*)l, 16, 0, 0);
}

// ---------------- fp32 -> bf16 bulk convert ----------------
__global__ void k_cvt(const float* __restrict__ src, u16* __restrict__ dst, int n4){
  int i = blockIdx.x*256 + threadIdx.x;
  if (i < n4){
    float4v v = ((const float4v*)src)[i];
    ushort4v o;
    o[0]=f2bf(v[0]); o[1]=f2bf(v[1]); o[2]=f2bf(v[2]); o[3]=f2bf(v[3]);
    ((ushort4v*)dst)[i] = o;
  }
}

// ---------------- fp32 -> split bf16 (hi + lo residual); also init atomics ----
__global__ void k_cvt2(const float* __restrict__ src, u16* __restrict__ hi,
                       u16* __restrict__ lo, int n4,
                       float* __restrict__ rowsum, float* __restrict__ picked){
  int i = blockIdx.x*256 + threadIdx.x;
  if (i < 2048){ rowsum[i] = 0.f; picked[i] = 0.f; }
  if (i < n4){
    float4v v = ((const float4v*)src)[i];
    ushort4v h, l;
    #pragma unroll
    for (int j=0;j<4;j++){ h[j]=f2bf(v[j]); l[j]=f2bf(v[j]-bf2f((u16)h[j])); }
    ((ushort4v*)hi)[i] = h;
    ((ushort4v*)lo)[i] = l;
  }
}

// ---------------- gather + stdnorm + noise; seeds Krylov k=0 block ----------
// V layout: row = k*128 + s, s=0..63 batch seeds, s=64 bias, s=65..127 zero pad.
__global__ void k_prep(const int* __restrict__ zi, const float* __restrict__ latent,
                       const float* __restrict__ noise, const float* __restrict__ tb,
                       float* __restrict__ z0, u16* __restrict__ V){
  __shared__ float sh[8];
  int b = blockIdx.x;
  if (b == 64){
    for (int e=threadIdx.x;e<1024;e+=256) V[(size_t)64*1024+e] = f2bf(tb[e]);
    for (int r=65;r<128;r++)
      for (int e=threadIdx.x;e<1024;e+=256) V[(size_t)r*1024+e] = 0;
    return;
  }
  const float* lat = latent + (size_t)zi[b]*2048;
  for (int j=0;j<2;j++){
    float s=0.f,q=0.f;
    for (int e=threadIdx.x;e<1024;e+=256){ float v=lat[j*1024+e]; s+=v; q+=v*v; }
    blockReduce2(s,q,sh);
    float sd = sqrtf(fmaxf(0.f,(q - s*s*(1.f/1024.f))*(1.f/1023.f)));
    float fac = 0.113f/(1e-5f+sd);
    for (int e=threadIdx.x;e<1024;e+=256){
      float v = lat[j*1024+e]*fac + (noise[((size_t)b*2+j)*1024+e]-0.5f)*0.05f;
      if (j==0) z0[b*1024+e]=v;
      else      V[(size_t)b*1024+e]=f2bf(v);
    }
  }
}

// ---------------- ek/ev projection: (64 x 16384) = z0 @ Wt, MFMA ----------------
__global__ __launch_bounds__(256) void k_ekev(const float* __restrict__ z0,
    const float* __restrict__ ekw, const float* __restrict__ ekb,
    const float* __restrict__ evw, const float* __restrict__ evb,
    float* __restrict__ ek_raw, float* __restrict__ ev_raw){
  int nb = blockIdx.x;
  const float* wsrc; const float* bsrc; float* dst;
  if (nb < 1024){ wsrc=ekw; bsrc=ekb; dst=ek_raw; }
  else          { wsrc=evw; bsrc=evb; dst=ev_raw; nb -= 1024; }
  int colbase = nb*16;
  int w = threadIdx.x>>6, lane = threadIdx.x&63;
  int m16 = lane&15, q = lane>>4;
  const float* za = z0 + (w*16+m16)*1024 + q*8;
  const float* wb = wsrc + ((size_t)(colbase+m16))*1024 + q*8;
  float4v acc = {0.f,0.f,0.f,0.f};
  for (int kk=0;kk<32;kk++){
    float4v a0 = *(const float4v*)(za + kk*32);
    float4v a1 = *(const float4v*)(za + kk*32 + 4);
    float4v b0 = *(const float4v*)(wb + kk*32);
    float4v b1 = *(const float4v*)(wb + kk*32 + 4);
    short8 af = pack8s(a0,a1,1.f);
    short8 bf = pack8s(b0,b1,1.f);
    acc = __builtin_amdgcn_mfma_f32_16x16x32_bf16(af,bf,acc,0,0,0);
  }
  float bias = bsrc[colbase+m16];
  for (int reg=0;reg<4;reg++){
    int r = w*16 + q*4 + reg;
    dst[(size_t)r*16384 + colbase + m16] = acc[reg] + bias;
  }
}

// ---------------- per-(b,m) stdnorm -> bf16 ----------------
__global__ void k_norm(const float* __restrict__ ek_raw, const float* __restrict__ ev_raw,
                       u16* __restrict__ ek16, u16* __restrict__ ev16){
  __shared__ float sh[8];
  int rr = blockIdx.x;
  const float* src = (rr<1024)? ek_raw : ev_raw;
  u16* dst = (rr<1024)? ek16 : ev16;
  int r = rr & 1023;
  const float* x = src + (size_t)r*1024;
  float s=0.f,q=0.f;
  for (int e=threadIdx.x;e<1024;e+=256){ float v=x[e]; s+=v; q+=v*v; }
  blockReduce2(s,q,sh);
  float fac = 0.113f/(1e-5f+sqrtf(fmaxf(0.f,(q-s*s*(1.f/1024.f))*(1.f/1023.f))));
  u16* o = dst + (size_t)r*1024;
  for (int e=threadIdx.x;e<1024;e+=256) o[e] = f2bf(x[e]*fac);
}

// ---------------- bf16 transpose, 2 planes (1024x1024) ----------------
__global__ __launch_bounds__(256) void k_tr(const u16* __restrict__ S1, u16* __restrict__ D1,
                                            const u16* __restrict__ S2, u16* __restrict__ D2){
  __shared__ u16 t[64*65];
  const u16* src = blockIdx.z ? S2 : S1;
  u16* dst = blockIdx.z ? D2 : D1;
  int bx = blockIdx.x, by = blockIdx.y, tid = threadIdx.x;
  #pragma unroll
  for (int i=0;i<4;i++){
    int r = i*16 + (tid>>4), c0 = (tid&15)*4;
    ushort4v v = *(const ushort4v*)(src + (size_t)(by*64+r)*1024 + bx*64 + c0);
    #pragma unroll
    for (int j=0;j<4;j++) t[(c0+j)*65 + r] = v[j];
  }
  __syncthreads();
  #pragma unroll
  for (int i=0;i<4;i++){
    int r2 = i*16 + (tid>>4), c0 = (tid&15)*4;
    ushort4v o;
    #pragma unroll
    for (int j=0;j<4;j++) o[j] = t[r2*65 + c0 + j];
    *(ushort4v*)(dst + (size_t)(bx*64+r2)*1024 + by*64 + c0) = o;
  }
}

// ---------------- split-bf16 matrix square body: C = (Ah+Al)(Bh+Bl)^T ---------
// 128x128 tile, swizzled LDS staging. Outputs hi (+optional lo, +optional
// transposed hi/lo planes, written scattered-in-32B-windows).
__device__ void sq_body(u16* sm, const u16* Ah, const u16* Al,
    const u16* Bh, const u16* Bl,
    u16* Ch, u16* Cl, u16* ChT, u16* ClT, int bm, int bn){
  u16* sAh = sm; u16* sAl = sm+8192; u16* sBh = sm+16384; u16* sBl = sm+24576;
  int tid = threadIdx.x;
  int w = tid>>6, lane = tid&63;
  int wm = w>>1, wn = w&1, m16 = lane&15, q = lane>>4;
  const u16* Abh = Ah + (size_t)bm*128*1024;
  const u16* Abl = Al + (size_t)bm*128*1024;
  const u16* Bbh = Bh + (size_t)bn*128*1024;
  const u16* Bbl = Bl + (size_t)bn*128*1024;
  float4v acc[4][4];
  for (int i=0;i<4;i++) for (int j=0;j<4;j++) acc[i][j] = (float4v){0.f,0.f,0.f,0.f};
  for (int kt=0;kt<16;kt++){
    int kb = kt*64;
    for (int rd=0; rd<4; rd++){
      int c = rd*256 + tid;
      int row = c>>3;
      int kq = (c&7) ^ (row&7);
      size_t go = (size_t)row*1024 + kb + kq*8;
      gll16(Abh+go, &sAh[c*8]); gll16(Abl+go, &sAl[c*8]);
      gll16(Bbh+go, &sBh[c*8]); gll16(Bbl+go, &sBl[c*8]);
    }
    __syncthreads();
    for (int s=0;s<2;s++){
      int kq = s*4 + q;
      short8 ah[4], al[4], bh[4], bl[4];
      for (int i=0;i<4;i++){
        int row = wm*64 + i*16 + m16;
        int offA = (row*8 + (kq ^ (row&7)))*8;
        ah[i] = *(const short8*)&sAh[offA];
        al[i] = *(const short8*)&sAl[offA];
        int col = wn*64 + i*16 + m16;
        int offB = (col*8 + (kq ^ (col&7)))*8;
        bh[i] = *(const short8*)&sBh[offB];
        bl[i] = *(const short8*)&sBl[offB];
      }
      for (int i=0;i<4;i++)
        for (int j=0;j<4;j++){
          acc[i][j] = __builtin_amdgcn_mfma_f32_16x16x32_bf16(al[i],bh[j],acc[i][j],0,0,0);
          acc[i][j] = __builtin_amdgcn_mfma_f32_16x16x32_bf16(ah[i],bl[j],acc[i][j],0,0,0);
          acc[i][j] = __builtin_amdgcn_mfma_f32_16x16x32_bf16(ah[i],bh[j],acc[i][j],0,0,0);
        }
    }
    __syncthreads();
  }
  for (int i=0;i<4;i++)
    for (int reg=0;reg<4;reg++){
      int r = bm*128 + wm*64 + i*16 + q*4 + reg;
      for (int j=0;j<4;j++){
        int c = bn*128 + wn*64 + j*16 + m16;
        float v = acc[i][j][reg];
        u16 h = f2bf(v);
        u16 lo = f2bf(v - bf2f(h));
        Ch[(size_t)r*1024+c] = h;
        if (Cl)  Cl[(size_t)r*1024+c] = lo;
        if (ChT) ChT[(size_t)c*1024+r] = h;
        if (ClT) ClT[(size_t)c*1024+r] = lo;
      }
    }
}

// ---------------- Krylov stage GEMM body: C[128rows] = A @ Bh^T --------------
__device__ void stage_body(u16* sm, const u16* A, const u16* Bh, u16* C,
                           int bm, int bn){
  u16* sA = sm; u16* sB = sm+8192;
  int tid = threadIdx.x;
  int w = tid>>6, lane = tid&63;
  int wm = w>>1, wn = w&1, m16 = lane&15, q = lane>>4;
  const u16* Ab = A + (size_t)bm*128*1024;
  const u16* Bb = Bh + (size_t)bn*128*1024;
  float4v acc[4][4];
  for (int i=0;i<4;i++) for (int j=0;j<4;j++) acc[i][j] = (float4v){0.f,0.f,0.f,0.f};
  for (int kt=0;kt<16;kt++){
    int kb = kt*64;
    for (int rd=0; rd<4; rd++){
      int c = rd*256 + tid;
      int row = c>>3;
      int kq = (c&7) ^ (row&7);
      size_t go = (size_t)row*1024 + kb + kq*8;
      gll16(Ab+go, &sA[c*8]);
      gll16(Bb+go, &sB[c*8]);
    }
    __syncthreads();
    for (int s=0;s<2;s++){
      int kq = s*4 + q;
      short8 af[4], bf[4];
      for (int i=0;i<4;i++){
        int row = wm*64 + i*16 + m16;
        af[i] = *(const short8*)&sA[(row*8 + (kq ^ (row&7)))*8];
        int col = wn*64 + i*16 + m16;
        bf[i] = *(const short8*)&sB[(col*8 + (kq ^ (col&7)))*8];
      }
      for (int i=0;i<4;i++)
        for (int j=0;j<4;j++)
          acc[i][j] = __builtin_amdgcn_mfma_f32_16x16x32_bf16(af[i],bf[j],acc[i][j],0,0,0);
    }
    __syncthreads();
  }
  for (int i=0;i<4;i++)
    for (int reg=0;reg<4;reg++){
      int r = bm*128 + wm*64 + i*16 + q*4 + reg;
      for (int j=0;j<4;j++){
        int c = bn*128 + wn*64 + j*16 + m16;
        C[(size_t)r*1024+c] = f2bf(acc[i][j][reg]);
      }
    }
}

__global__ __launch_bounds__(256) void k_stage(const u16* __restrict__ A,
    const u16* __restrict__ Bh, u16* __restrict__ C){
  __shared__ u16 sm[16384];
  stage_body(sm, A, Bh, C, blockIdx.x, blockIdx.y);
}

// ---------------- merged level: blocks 0..63 square, rest do a V-stage -------
__global__ __launch_bounds__(256) void k_level(const u16* __restrict__ Ah,
    const u16* __restrict__ Al, const u16* __restrict__ Bh, const u16* __restrict__ Bl,
    u16* __restrict__ Ch, u16* __restrict__ Cl, u16* __restrict__ ChT, u16* __restrict__ ClT,
    const u16* __restrict__ Vin, const u16* __restrict__ Wst, u16* __restrict__ Vout){
  __shared__ u16 sm[32768];
  if (blockIdx.x < 64){
    sq_body(sm, Ah, Al, Bh, Bl, Ch, Cl, ChT, ClT, (int)(blockIdx.x>>3), (int)(blockIdx.x&7));
  } else {
    int s = blockIdx.x - 64;
    stage_body(sm, Vin, Wst, Vout, s>>3, s&7);
  }
}

// ---------------- fused gram + scalar Krylov scan + emit ----------------
// per-batch block: Gram G[64x64], proj P[64x16], sums S[64] in LDS; 32-step
// gamma scan on wave 0; emit zs[b,t,:] from LDS-resident ev.
__global__ __launch_bounds__(256) void k_gramscan(const u16* __restrict__ V,
    const u16* __restrict__ ek16, const u16* __restrict__ ev16,
    u16* __restrict__ zs16){
  __shared__ float gG[64*65];
  __shared__ float pl[1024];
  __shared__ float sS[64];
  __shared__ float attL[32][16];
  __shared__ u16  evs[16*1024];
  __shared__ float red[256];
  __shared__ __align__(16) float gam[64];
  int b = blockIdx.x, tid = threadIdx.x;
  int w = tid>>6, lane = tid&63, m16 = lane&15, q = lane>>4;

  // stage ev[b] into LDS (32 KB)
  for (int i=tid; i<4096; i+=256)
    ((ushort4v*)evs)[i] = ((const ushort4v*)(ev16 + (size_t)b*16*1024))[i];

  // ---- Gram via MFMA ----
  int kap = w*16 + m16;
  size_t arow = (kap<32) ? ((size_t)kap*128 + b) : ((size_t)(kap-32)*128 + 64);
  const u16* ap = V + arow*1024 + q*8;
  const u16* bp[5];
  #pragma unroll
  for (int j=0;j<4;j++){
    int y = j*16 + m16;
    size_t br = (y<32) ? ((size_t)y*128 + b) : ((size_t)(y-32)*128 + 64);
    bp[j] = V + br*1024 + q*8;
  }
  bp[4] = ek16 + ((size_t)(b*16 + m16))*1024 + q*8;
  float4v acc[5];
  #pragma unroll
  for (int j=0;j<5;j++) acc[j] = (float4v){0.f,0.f,0.f,0.f};
  for (int kk=0;kk<32;kk++){
    short8 a8 = *(const short8*)(ap + kk*32);
    #pragma unroll
    for (int j=0;j<5;j++){
      short8 b8 = *(const short8*)(bp[j] + kk*32);
      acc[j] = __builtin_amdgcn_mfma_f32_16x16x32_bf16(a8,b8,acc[j],0,0,0);
    }
  }
  int kbase = w*16 + q*4;
  for (int j=0;j<5;j++)
    for (int reg=0;reg<4;reg++){
      int y = j*16 + m16;
      float v = acc[j][reg];
      if (j<4) gG[(kbase+reg)*65 + y] = v;
      else     pl[(kbase+reg)*16 + (y-64)] = v;
    }
  // element sums S[kappa]
  {
    int kap2 = tid>>2, seg = tid&3;
    size_t row2 = (kap2<32) ? ((size_t)kap2*128 + b) : ((size_t)(kap2-32)*128 + 64);
    const u16* vp = V + row2*1024 + seg*256;
    float sum = 0.f;
    for (int i=0;i<32;i++){
      short8 v8 = *(const short8*)(vp + i*8);
      #pragma unroll
      for (int e=0;e<8;e++) sum += bf2f((u16)v8[e]);
    }
    red[tid] = sum;
  }
  __syncthreads();
  if (tid<64) sS[tid] = red[tid*4]+red[tid*4+1]+red[tid*4+2]+red[tid*4+3];
  __syncthreads();

  // ---- scan (wave 0 only; all threads hit barriers) ----
  bool act = (tid < 64);
  float gr[64]; float s_own=0.f, g_own=0.f;
  if (act){
    #pragma unroll
    for (int i=0;i<64;i++) gr[i] = gG[lane*65 + i];
    s_own = sS[lane];
    g_own = (lane==0) ? 1.f : 0.f;
    gam[lane] = g_own;
  }
  __syncthreads();
  for (int t=0;t<32;t++){
    float f = 0.f, prev = 0.f;
    if (act){
      float r = 0.f;
      #pragma unroll
      for (int i=0;i<64;i++) r += gr[i]*gam[i];
      float qq = g_own*r, sm = g_own*s_own;
      for (int m=32;m>=1;m>>=1){ qq += __shfl_xor(qq,m,64); sm += __shfl_xor(sm,m,64); }
      float var = (qq - sm*sm*(1.f/1024.f))*(1.f/1023.f);
      f = 0.113f/(1e-5f + sqrtf(fmaxf(0.f,var)));
      float sc = 0.f;
      if (lane < 16){
        #pragma unroll
        for (int k2=0;k2<64;k2++) sc += gam[k2]*pl[k2*16+lane];
        sc *= f;
      }
      float mx = sc;
      for (int m=8;m>=1;m>>=1) mx = fmaxf(mx, __shfl_xor(mx,m,64));
      float ex = __expf(sc - mx), ss = ex;
      for (int m=8;m>=1;m>>=1) ss += __shfl_xor(ss,m,64);
      if (lane<16) attL[t][lane] = ex/ss;
      prev = (lane==0 || lane==32) ? 0.f : gam[lane-1];
    }
    __syncthreads();
    if (act){ g_own = (lane==32) ? 0.5f : 0.5f*f*prev; gam[lane] = g_own; }
    __syncthreads();
  }

  // ---- emit: zs[b,t,:] = sum_m att[t][m] * ev[m,:] ----
  for (int t=0;t<32;t++){
    float o0=0,o1=0,o2=0,o3=0;
    #pragma unroll
    for (int m=0;m<16;m++){
      float a = attL[t][m];
      ushort4v v = *(const ushort4v*)&evs[m*1024 + tid*4];
      o0 += a*bf2f(v[0]); o1 += a*bf2f(v[1]); o2 += a*bf2f(v[2]); o3 += a*bf2f(v[3]);
    }
    ushort4v o; o[0]=f2bf(o0); o[1]=f2bf(o1); o[2]=f2bf(o2); o[3]=f2bf(o3);
    *(ushort4v*)(zs16 + ((size_t)(b*32+t))*1024 + tid*4) = o;
  }
}

// ---------------- logits GEMM 2048x32000x1024 bf16, 256^2 tile, 2-phase dbuf ---
// (reverted to the measured-best R2 structure)
__global__ __launch_bounds__(512,2) void k_logits(const u16* __restrict__ A,
    const u16* __restrict__ Bt, const float* __restrict__ vb,
    const int* __restrict__ y, float* __restrict__ rowsum, float* __restrict__ picked){
  __shared__ u16 sA[2][16384];
  __shared__ u16 sB[2][16384];
  int lin = blockIdx.y*8 + blockIdx.x;
  int newlin = (lin&7)*125 + (lin>>3);      // each XCD gets contiguous bn range
  int bm = newlin&7, bn = newlin>>3;
  int tid = threadIdx.x;
  int w = tid>>6, lane = tid&63;
  int wm = w>>2, wn = w&3, m16 = lane&15, q = lane>>4;
  int sw = m16&7;
  const u16* Ab = A  + (size_t)bm*256*1024;
  const u16* Bb = Bt + (size_t)bn*256*1024;
  float4v acc[8][4];
  #pragma unroll
  for (int i=0;i<8;i++)
    #pragma unroll
    for (int j=0;j<4;j++) acc[i][j] = (float4v){0.f,0.f,0.f,0.f};

  #define STAGE(kt_, buf_) do {                                         \
    int kb_ = (kt_)*64;                                                 \
    _Pragma("unroll")                                                   \
    for (int l_=0;l_<4;l_++){                                           \
      int c_ = l_*512 + tid;                                            \
      int row_ = c_>>3;                                                 \
      int kq_ = (c_&7) ^ (row_&7);                                      \
      gll16(Ab + (size_t)row_*1024 + kb_ + kq_*8, &sA[buf_][c_*8]);     \
      gll16(Bb + (size_t)row_*1024 + kb_ + kq_*8, &sB[buf_][c_*8]);     \
    }                                                                   \
  } while(0)

  STAGE(0, 0);
  __syncthreads();
  for (int kt=0; kt<16; kt++){
    int cur = kt&1;
    if (kt < 15) STAGE(kt+1, cur^1);
    #pragma unroll
    for (int s=0;s<2;s++){
      int kq = s*4 + q;
      short8 af[8], bf[4];
      #pragma unroll
      for (int i=0;i<8;i++){
        int row = wm*128 + i*16 + m16;
        af[i] = *(const short8*)&sA[cur][row*64 + (kq^sw)*8];
      }
      #pragma unroll
      for (int j=0;j<4;j++){
        int col = wn*64 + j*16 + m16;
        bf[j] = *(const short8*)&sB[cur][col*64 + (kq^sw)*8];
      }
      #pragma unroll
      for (int i=0;i<8;i++)
        #pragma unroll
        for (int j=0;j<4;j++)
          acc[i][j] = __builtin_amdgcn_mfma_f32_16x16x32_bf16(af[i],bf[j],acc[i][j],0,0,0);
    }
    __syncthreads();
  }
  #undef STAGE

  // fused logsumexp epilogue
  #pragma unroll
  for (int i=0;i<8;i++){
    #pragma unroll
    for (int reg=0;reg<4;reg++){
      int r = bm*256 + wm*128 + i*16 + q*4 + reg;
      int yt = y[r];
      float rs = 0.f;
      #pragma unroll
      for (int j=0;j<4;j++){
        int gcol = bn*256 + wn*64 + j*16 + m16;
        float val = acc[i][j][reg] + vb[gcol];
        rs += __expf(val);
        if (gcol == yt) picked[r] = val;
      }
      for (int mm=1;mm<16;mm<<=1) rs += __shfl_xor(rs,mm,16);
      if (m16==0) atomicAdd(&rowsum[r], rs);
    }
  }
}

__global__ void k_final(const float* __restrict__ picked, const float* __restrict__ rowsum,
                        float* __restrict__ out){
  int r = blockIdx.x*256 + threadIdx.x;
  if (r < 2048) out[r] = picked[r] - logf(rowsum[r]);
}

extern "C" void kernel_launch(void* const* d_in, const int* in_sizes, int n_in,
                              void* d_out, int out_size, void* d_ws, size_t ws_size,
                              hipStream_t stream){
  (void)in_sizes; (void)n_in; (void)out_size; (void)ws_size;
  const int*   zi     = (const int*)d_in[0];
  const int*   y      = (const int*)d_in[1];
  const float* noise  = (const float*)d_in[2];
  const float* latent = (const float*)d_in[3];
  const float* transw = (const float*)d_in[4];
  const float* transb = (const float*)d_in[5];
  const float* ekw    = (const float*)d_in[6];
  const float* ekb    = (const float*)d_in[7];
  const float* evw    = (const float*)d_in[8];
  const float* evb    = (const float*)d_in[9];
  const float* vw     = (const float*)d_in[10];
  const float* vbias  = (const float*)d_in[11];
  float* out = (float*)d_out;

  const size_t MPLANE = (size_t)1024*1024;   // one 1024x1024 bf16 plane (elems)
  char* p = (char*)d_ws;
  u16* vocab16 = (u16*)p;  p += (size_t)32000*1024*2;
  u16* Whi  = (u16*)p;  p += MPLANE*2;
  u16* Wlo  = (u16*)p;  p += MPLANE*2;
  u16* P1h  = (u16*)p;  p += MPLANE*2;
  u16* P1l  = (u16*)p;  p += MPLANE*2;
  u16* T2h  = (u16*)p;  p += MPLANE*2;
  u16* T2l  = (u16*)p;  p += MPLANE*2;
  u16* P2h  = (u16*)p;  p += MPLANE*2;
  u16* P2l  = (u16*)p;  p += MPLANE*2;
  u16* T4h  = (u16*)p;  p += MPLANE*2;
  u16* T4l  = (u16*)p;  p += MPLANE*2;
  u16* P4h  = (u16*)p;  p += MPLANE*2;
  u16* P4l  = (u16*)p;  p += MPLANE*2;
  u16* T8h  = (u16*)p;  p += MPLANE*2;
  u16* V    = (u16*)p;  p += (size_t)4096*1024*2;   // 32 k-blocks x 128 rows
  u16* zs16 = (u16*)p;  p += (size_t)2048*1024*2;
  u16* ek16 = (u16*)p;  p += (size_t)64*16*1024*2;
  u16* ev16 = (u16*)p;  p += (size_t)64*16*1024*2;
  float* ekraw = (float*)p; p += (size_t)64*16384*4;
  float* evraw = (float*)p; p += (size_t)64*16384*4;
  float* z0    = (float*)p; p += (size_t)64*1024*4;
  float* rowsum= (float*)p; p += (size_t)2048*4;
  float* picked= (float*)p; p += (size_t)2048*4;

  hipLaunchKernelGGL(k_cvt2, dim3(1024),  dim3(256), 0, stream, transw, Whi, Wlo, 1024*1024/4, rowsum, picked);
  hipLaunchKernelGGL(k_cvt,  dim3(32000), dim3(256), 0, stream, vw, vocab16, 32000*1024/4);
  hipLaunchKernelGGL(k_prep, dim3(65),    dim3(256), 0, stream, zi, latent, noise, transb, z0, V);
  hipLaunchKernelGGL(k_ekev, dim3(2048),  dim3(256), 0, stream, z0, ekw, ekb, evw, evb, ekraw, evraw);
  hipLaunchKernelGGL(k_norm, dim3(2048),  dim3(256), 0, stream, ekraw, evraw, ek16, ev16);

  // W^T planes for level 0
  hipLaunchKernelGGL(k_tr, dim3(16,16,2), dim3(256), 0, stream, Whi, P1h, Wlo, P1l);
  // level 0: W^2 (+transposes) || V-stage with W     (64 + 8 blocks)
  hipLaunchKernelGGL(k_level, dim3(72), dim3(256), 0, stream,
      Whi, Wlo, P1h, P1l, T2h, T2l, P2h, P2l, V, Whi, V + (size_t)1*128*1024);
  // level 1: W^4 (+transposes) || V-stage with W^2   (64 + 16 blocks)
  hipLaunchKernelGGL(k_level, dim3(80), dim3(256), 0, stream,
      T2h, T2l, P2h, P2l, T4h, T4l, P4h, P4l, V, T2h, V + (size_t)2*128*1024);
  // level 2: W^8 (hi only)     || V-stage with W^4   (64 + 32 blocks)
  hipLaunchKernelGGL(k_level, dim3(96), dim3(256), 0, stream,
      T4h, T4l, P4h, P4l, T8h, (u16*)nullptr, (u16*)nullptr, (u16*)nullptr,
      V, T4h, V + (size_t)4*128*1024);
  // remaining stages: chain through W^8 (no W^16 needed)
  hipLaunchKernelGGL(k_stage, dim3(8,8), dim3(256), 0, stream, V,                        T8h, V + (size_t)8*128*1024);
  hipLaunchKernelGGL(k_stage, dim3(8,8), dim3(256), 0, stream, V + (size_t)8*128*1024,  T8h, V + (size_t)16*128*1024);
  hipLaunchKernelGGL(k_stage, dim3(8,8), dim3(256), 0, stream, V + (size_t)16*128*1024, T8h, V + (size_t)24*128*1024);

  hipLaunchKernelGGL(k_gramscan, dim3(64), dim3(256), 0, stream, V, ek16, ev16, zs16);
  hipLaunchKernelGGL(k_logits,  dim3(8,125), dim3(512), 0, stream, zs16, vocab16, vbias, y, rowsum, picked);
  hipLaunchKernelGGL(k_final,   dim3(8),    dim3(256), 0, stream, picked, rowsum, out);
}